// Round 2
// baseline (1185.520 us; speedup 1.0000x reference)
//
#include <hip/hip_runtime.h>

#define B_  16
#define C_  256
#define N_  1024
#define H_  4
#define HD_ 64

// ---------------- transpose: x[b][c][n] -> xf[b][n][c] ----------------
__global__ __launch_bounds__(256) void k_transpose(const float* __restrict__ x,
                                                   float* __restrict__ xf) {
    __shared__ float tile[32][33];
    int b = blockIdx.z;
    int n0 = blockIdx.x * 32, c0 = blockIdx.y * 32;
    int tx = threadIdx.x, ty = threadIdx.y;  // 32 x 8
    const float* xb = x + (size_t)b * C_ * N_;
    float* xfb = xf + (size_t)b * N_ * C_;
#pragma unroll
    for (int i = 0; i < 4; i++)
        tile[ty + i * 8][tx] = xb[(size_t)(c0 + ty + i * 8) * N_ + n0 + tx];
    __syncthreads();
#pragma unroll
    for (int i = 0; i < 4; i++)
        xfb[(size_t)(n0 + ty + i * 8) * C_ + c0 + tx] = tile[tx][ty + i * 8];
}

// ---------------- GEMM: C[b] = A[b] @ W^T (+bias) ----------------
// A: [M,256] row-major per batch, W: [Nout,256] row-major, C: [M,Nout]
// BM=64, BN=64, BK=32, 256 threads, 4x4 per thread
__global__ __launch_bounds__(256) void k_gemm_bt(const float* __restrict__ A,
                                                 const float* __restrict__ W,
                                                 const float* __restrict__ bias,
                                                 float* __restrict__ C,
                                                 int M, int Nout) {
    constexpr int K = 256;
    __shared__ float As[32][68];
    __shared__ float Ws[32][68];
    int b = blockIdx.z;
    int n0 = blockIdx.x * 64;
    int m0 = blockIdx.y * 64;
    const float* Ab = A + (size_t)b * M * K + (size_t)m0 * K;
    const float* Wb = W + (size_t)n0 * K;
    float* Cb = C + (size_t)b * M * Nout + (size_t)m0 * Nout + n0;
    int t = threadIdx.x;
    int ty = t >> 4, tx = t & 15;
    int lr0 = t >> 3, lc0 = t & 7;
    float acc[4][4] = {};
    for (int k0 = 0; k0 < K; k0 += 32) {
#pragma unroll
        for (int e = 0; e < 2; e++) {
            int row = lr0 + e * 32;
            float4 va = *reinterpret_cast<const float4*>(&Ab[(size_t)row * K + k0 + lc0 * 4]);
            As[lc0 * 4 + 0][row] = va.x;
            As[lc0 * 4 + 1][row] = va.y;
            As[lc0 * 4 + 2][row] = va.z;
            As[lc0 * 4 + 3][row] = va.w;
            float4 vw = *reinterpret_cast<const float4*>(&Wb[(size_t)row * K + k0 + lc0 * 4]);
            Ws[lc0 * 4 + 0][row] = vw.x;
            Ws[lc0 * 4 + 1][row] = vw.y;
            Ws[lc0 * 4 + 2][row] = vw.z;
            Ws[lc0 * 4 + 3][row] = vw.w;
        }
        __syncthreads();
#pragma unroll
        for (int k = 0; k < 32; k++) {
            float4 av = *reinterpret_cast<const float4*>(&As[k][ty * 4]);
            float4 bv = *reinterpret_cast<const float4*>(&Ws[k][tx * 4]);
            float aa[4] = {av.x, av.y, av.z, av.w};
            float bb[4] = {bv.x, bv.y, bv.z, bv.w};
#pragma unroll
            for (int i = 0; i < 4; i++)
#pragma unroll
                for (int j = 0; j < 4; j++)
                    acc[i][j] += aa[i] * bb[j];
        }
        __syncthreads();
    }
#pragma unroll
    for (int i = 0; i < 4; i++) {
        int m = ty * 4 + i;
        float4 o;
        o.x = acc[i][0]; o.y = acc[i][1]; o.z = acc[i][2]; o.w = acc[i][3];
        if (bias) {
            o.x += bias[n0 + tx * 4 + 0];
            o.y += bias[n0 + tx * 4 + 1];
            o.z += bias[n0 + tx * 4 + 2];
            o.w += bias[n0 + tx * 4 + 3];
        }
        *reinterpret_cast<float4*>(&Cb[(size_t)m * Nout + tx * 4]) = o;
    }
}

// ---------------- depthwise 3x3 conv + bias + residual add ----------------
__global__ __launch_bounds__(256) void k_dwconv_add(const float* __restrict__ yp,
                                                    const float* __restrict__ dw_w,
                                                    const float* __restrict__ dw_b,
                                                    float* __restrict__ out) {
    int b = blockIdx.y;
    int n = blockIdx.x;
    int cc = threadIdx.x;
    int yy = n >> 5, xx = n & 31;
    const float* ypb = yp + (size_t)b * N_ * C_;
    float acc = dw_b[cc];
#pragma unroll
    for (int dy = 0; dy < 3; dy++) {
        int y2 = yy + dy - 1;
        if (y2 < 0 || y2 >= 32) continue;
#pragma unroll
        for (int dx = 0; dx < 3; dx++) {
            int x2 = xx + dx - 1;
            if (x2 < 0 || x2 >= 32) continue;
            acc += ypb[(size_t)(y2 * 32 + x2) * C_ + cc] * dw_w[cc * 9 + dy * 3 + dx];
        }
    }
    out[(size_t)b * N_ * C_ + (size_t)n * C_ + cc] = acc + ypb[(size_t)n * C_ + cc];
}

// ---------------- flash attention (64 q-rows per block) ----------------
// Q: [b][n][h*64+d] (stride C_), KV: [b][n][t*256 + h*64+d] (stride 512)
// STAGE 0: Out = y[b][n][h*64+d]
// STAGE 1: Out = d_out scatter per the batch-mixing reshape:
//   bo = (n&1)*8 + h*2 + (b>>3); no = (b&7)*128 + (n>>3); co = ((n>>1)&3)*64 + d
template <int STAGE>
__global__ __launch_bounds__(256) void k_attn(const float* __restrict__ Q,
                                              const float* __restrict__ KV,
                                              float* __restrict__ Out) {
    __shared__ float Qs[64][68];
    __shared__ float Ks[64][68];
    __shared__ float Vs[64][68];
    __shared__ float Ss[64][68];
    __shared__ float rowfac[64];
    __shared__ float rowinv[64];
    int qt = blockIdx.x, h = blockIdx.y, b = blockIdx.z;
    int q0 = qt * 64;
    int t = threadIdx.x;
    int ty = t >> 4, tx = t & 15;
    int sr = t >> 2, scg = t & 3;
    const float* Qb = Q + ((size_t)b * N_ + q0) * C_ + h * HD_;
    const float* KVb = KV + (size_t)b * N_ * (2 * C_) + h * HD_;
#pragma unroll
    for (int e = 0; e < 4; e++) {
        int idx = t + e * 256;
        int row = idx >> 4, c4 = idx & 15;
        float4 v = *reinterpret_cast<const float4*>(&Qb[(size_t)row * C_ + c4 * 4]);
        v.x *= 0.125f; v.y *= 0.125f; v.z *= 0.125f; v.w *= 0.125f;
        *reinterpret_cast<float4*>(&Qs[row][c4 * 4]) = v;
    }
    float m_r = -1e30f, l_r = 0.0f;
    float accO[4][4] = {};
    for (int kb = 0; kb < 16; kb++) {
        __syncthreads();
#pragma unroll
        for (int e = 0; e < 4; e++) {
            int idx = t + e * 256;
            int row = idx >> 4, c4 = idx & 15;
            const float* src = &KVb[(size_t)(kb * 64 + row) * (2 * C_) + c4 * 4];
            *reinterpret_cast<float4*>(&Ks[row][c4 * 4]) =
                *reinterpret_cast<const float4*>(src);
            *reinterpret_cast<float4*>(&Vs[row][c4 * 4]) =
                *reinterpret_cast<const float4*>(src + C_);
        }
        __syncthreads();
        // S = Qs @ Ks^T
        float s[4][4] = {};
#pragma unroll
        for (int d0 = 0; d0 < 64; d0 += 4) {
            float qa[4][4], ka[4][4];
#pragma unroll
            for (int i = 0; i < 4; i++) {
                float4 v = *reinterpret_cast<const float4*>(&Qs[ty * 4 + i][d0]);
                qa[i][0] = v.x; qa[i][1] = v.y; qa[i][2] = v.z; qa[i][3] = v.w;
            }
#pragma unroll
            for (int j = 0; j < 4; j++) {
                float4 v = *reinterpret_cast<const float4*>(&Ks[tx * 4 + j][d0]);
                ka[j][0] = v.x; ka[j][1] = v.y; ka[j][2] = v.z; ka[j][3] = v.w;
            }
#pragma unroll
            for (int i = 0; i < 4; i++)
#pragma unroll
                for (int j = 0; j < 4; j++)
#pragma unroll
                    for (int d = 0; d < 4; d++)
                        s[i][j] += qa[i][d] * ka[j][d];
        }
#pragma unroll
        for (int i = 0; i < 4; i++) {
            float4 v;
            v.x = s[i][0]; v.y = s[i][1]; v.z = s[i][2]; v.w = s[i][3];
            *reinterpret_cast<float4*>(&Ss[ty * 4 + i][tx * 4]) = v;
        }
        __syncthreads();
        // online softmax: 4 lanes per row
        float tmax = -1e30f;
#pragma unroll
        for (int j = 0; j < 16; j++) tmax = fmaxf(tmax, Ss[sr][scg * 16 + j]);
        tmax = fmaxf(tmax, __shfl_xor(tmax, 1));
        tmax = fmaxf(tmax, __shfl_xor(tmax, 2));
        float mnew = fmaxf(m_r, tmax);
        float fac = __expf(m_r - mnew);
        float psum = 0.0f;
#pragma unroll
        for (int j = 0; j < 16; j++) {
            float p = __expf(Ss[sr][scg * 16 + j] - mnew);
            Ss[sr][scg * 16 + j] = p;
            psum += p;
        }
        psum += __shfl_xor(psum, 1);
        psum += __shfl_xor(psum, 2);
        l_r = l_r * fac + psum;
        m_r = mnew;
        if (scg == 0) rowfac[sr] = fac;
        __syncthreads();
        // O = O*fac + P @ V
        float fi[4];
#pragma unroll
        for (int i = 0; i < 4; i++) fi[i] = rowfac[ty * 4 + i];
#pragma unroll
        for (int i = 0; i < 4; i++)
#pragma unroll
            for (int j = 0; j < 4; j++) accO[i][j] *= fi[i];
#pragma unroll
        for (int k0 = 0; k0 < 64; k0 += 4) {
            float pa[4][4], va[4][4];
#pragma unroll
            for (int i = 0; i < 4; i++) {
                float4 v = *reinterpret_cast<const float4*>(&Ss[ty * 4 + i][k0]);
                pa[i][0] = v.x; pa[i][1] = v.y; pa[i][2] = v.z; pa[i][3] = v.w;
            }
#pragma unroll
            for (int kk = 0; kk < 4; kk++) {
                float4 v = *reinterpret_cast<const float4*>(&Vs[k0 + kk][tx * 4]);
                va[kk][0] = v.x; va[kk][1] = v.y; va[kk][2] = v.z; va[kk][3] = v.w;
            }
#pragma unroll
            for (int i = 0; i < 4; i++)
#pragma unroll
                for (int j = 0; j < 4; j++)
#pragma unroll
                    for (int kk = 0; kk < 4; kk++)
                        accO[i][j] += pa[i][kk] * va[kk][j];
        }
    }
    if (scg == 0) rowinv[sr] = 1.0f / l_r;
    __syncthreads();
    if (STAGE == 0) {
        float* Ob = Out + ((size_t)b * N_ + q0) * C_ + h * HD_;
#pragma unroll
        for (int i = 0; i < 4; i++) {
            int row = ty * 4 + i;
            float inv = rowinv[row];
            float4 v;
            v.x = accO[i][0] * inv; v.y = accO[i][1] * inv;
            v.z = accO[i][2] * inv; v.w = accO[i][3] * inv;
            *reinterpret_cast<float4*>(&Ob[(size_t)row * C_ + tx * 4]) = v;
        }
    } else {
        // batch-mixing scatter (see header comment)
#pragma unroll
        for (int i = 0; i < 4; i++) {
            int row = ty * 4 + i;
            int n = q0 + row;
            float inv = rowinv[row];
            int bo = (n & 1) * 8 + h * 2 + (b >> 3);
            int no = (b & 7) * 128 + (n >> 3);
            int cb = ((n >> 1) & 3) * 64 + tx * 4;
            float* Ob = Out + (size_t)bo * C_ * N_ + no;
#pragma unroll
            for (int j = 0; j < 4; j++)
                Ob[(size_t)(cb + j) * N_] = accO[i][j] * inv;
        }
    }
}

extern "C" void kernel_launch(void* const* d_in, const int* in_sizes, int n_in,
                              void* d_out, int out_size, void* d_ws, size_t ws_size,
                              hipStream_t stream) {
    const float* x      = (const float*)d_in[0];
    const float* q_w    = (const float*)d_in[1];
    const float* kv_w   = (const float*)d_in[2];
    const float* proj_w = (const float*)d_in[3];
    const float* proj_b = (const float*)d_in[4];
    const float* lq_w   = (const float*)d_in[5];
    const float* lq_b   = (const float*)d_in[6];
    const float* lkv_w  = (const float*)d_in[7];
    const float* lkv_b  = (const float*)d_in[8];
    // d_in[9] = rel_bias: constant along softmax axis -> no-op, skipped
    const float* dw_w   = (const float*)d_in[10];
    const float* dw_b   = (const float*)d_in[11];
    float* out = (float*)d_out;
    float* ws = (float*)d_ws;

    const size_t SZ = (size_t)B_ * N_ * C_;  // 4M floats
    float* xf   = ws;            // [0, SZ)
    float* qb   = ws + SZ;       // [SZ, 2SZ)
    float* kvb  = ws + 2 * SZ;   // [2SZ, 4SZ)
    float* yb   = ws + 4 * SZ;   // [4SZ, 5SZ)
    float* ypb  = qb;            // proj out reuses q
    float* s2in = kvb;           // conv-out+res reuses kv (first SZ)
    float* q2b  = yb;            // q2 reuses y
    float* kv2b = ws;            // kv2 reuses xf+q (2SZ floats)

    k_transpose<<<dim3(N_ / 32, C_ / 32, B_), dim3(32, 8), 0, stream>>>(x, xf);
    k_gemm_bt<<<dim3(4, 16, B_), 256, 0, stream>>>(xf, q_w, nullptr, qb, N_, C_);
    k_gemm_bt<<<dim3(8, 16, B_), 256, 0, stream>>>(xf, kv_w, nullptr, kvb, N_, 2 * C_);
    k_attn<0><<<dim3(16, H_, B_), 256, 0, stream>>>(qb, kvb, yb);
    k_gemm_bt<<<dim3(4, 16, B_), 256, 0, stream>>>(yb, proj_w, proj_b, ypb, N_, C_);
    k_dwconv_add<<<dim3(N_, B_), 256, 0, stream>>>(ypb, dw_w, dw_b, s2in);
    k_gemm_bt<<<dim3(4, 16, B_), 256, 0, stream>>>(xf, lq_w, lq_b, q2b, N_, C_);
    k_gemm_bt<<<dim3(8, 16, B_), 256, 0, stream>>>(s2in, lkv_w, lkv_b, kv2b, N_, 2 * C_);
    k_attn<1><<<dim3(16, H_, B_), 256, 0, stream>>>(q2b, kv2b, out);
}

// Round 3
// 250.512 us; speedup vs baseline: 4.7324x; 4.7324x over previous
//
#include <hip/hip_runtime.h>

#define B_  16
#define C_  256
#define N_  1024
#define H_  4

typedef unsigned short u16;
typedef __attribute__((ext_vector_type(8))) short bf16x8;
typedef __attribute__((ext_vector_type(4))) float f32x4;

__device__ __forceinline__ u16 f2bf(float f) {
    union { float f; unsigned u; } v; v.f = f;
    unsigned r = v.u + 0x7FFFu + ((v.u >> 16) & 1u);
    return (u16)(r >> 16);
}
__device__ __forceinline__ float bf2f(u16 h) {
    union { unsigned u; float f; } v; v.u = ((unsigned)h) << 16;
    return v.f;
}

// ---------------- weights f32 -> bf16 (4 elems/thread) ----------------
__global__ __launch_bounds__(256) void k_f2bf(const float* __restrict__ s,
                                              u16* __restrict__ d, int n4) {
    int i = blockIdx.x * 256 + threadIdx.x;
    if (i < n4) {
        float4 v = reinterpret_cast<const float4*>(s)[i];
        ushort4 o;
        o.x = f2bf(v.x); o.y = f2bf(v.y); o.z = f2bf(v.z); o.w = f2bf(v.w);
        reinterpret_cast<ushort4*>(d)[i] = o;
    }
}

// ---------------- x[b][c][n] f32 -> xf[b][n][c] bf16 ----------------
__global__ __launch_bounds__(256) void k_transpose_x(const float* __restrict__ x,
                                                     u16* __restrict__ xf) {
    __shared__ u16 tile[32][33];
    int b = blockIdx.z;
    int n0 = blockIdx.x * 32, c0 = blockIdx.y * 32;
    int tx = threadIdx.x, ty = threadIdx.y;  // 32 x 8
#pragma unroll
    for (int i = 0; i < 4; i++)
        tile[ty + i * 8][tx] =
            f2bf(x[((size_t)(b * C_ + c0 + ty + i * 8)) * N_ + n0 + tx]);
    __syncthreads();
#pragma unroll
    for (int i = 0; i < 4; i++)
        xf[((size_t)(b * N_ + n0 + ty + i * 8)) * C_ + c0 + tx] = tile[tx][ty + i * 8];
}

// ---------------- V part of kv[b][n][512] -> Vt[b][h][d][n] bf16 ----------------
__global__ __launch_bounds__(256) void k_transposeV(const u16* __restrict__ kv,
                                                    u16* __restrict__ Vt) {
    __shared__ u16 tile[32][33];
    int b = blockIdx.z;
    int n0 = blockIdx.x * 32, vc0 = blockIdx.y * 32;  // vc0 in [0,256)
    int h = vc0 >> 6, dl = vc0 & 63;
    int tx = threadIdx.x, ty = threadIdx.y;
#pragma unroll
    for (int i = 0; i < 4; i++)
        tile[ty + i * 8][tx] =
            kv[((size_t)(b * N_ + n0 + ty + i * 8)) * 512 + 256 + vc0 + tx];
    __syncthreads();
#pragma unroll
    for (int i = 0; i < 4; i++)
        Vt[((size_t)((b * H_ + h) * 64 + dl + ty + i * 8)) * N_ + n0 + tx] =
            tile[tx][ty + i * 8];
}

// ---------------- MFMA GEMM: C[m][n] = A[m][:] . W[n][:] (+bias) ----------------
// A: [16384,256] bf16, W: [Nout,256] bf16, C: [16384,Nout] bf16
// block 256 thr = 4 waves (2x2), tile 128x128, BK=32
__global__ __launch_bounds__(256) void k_gemm_bf16(const u16* __restrict__ A,
                                                   const u16* __restrict__ W,
                                                   const float* __restrict__ bias,
                                                   u16* __restrict__ C, int Nout) {
    __shared__ u16 As[128][40];
    __shared__ u16 Bs[128][40];
    int m0 = blockIdx.y * 128, n0 = blockIdx.x * 128;
    int t = threadIdx.x;
    int wid = t >> 6, lane = t & 63;
    int l16 = lane & 15, g = lane >> 4;
    int wm = (wid >> 1) * 64, wn = (wid & 1) * 64;
    int srow = t >> 1, scol = (t & 1) * 16;
    f32x4 zz = {0.f, 0.f, 0.f, 0.f};
    f32x4 acc[4][4];
#pragma unroll
    for (int i = 0; i < 4; i++)
#pragma unroll
        for (int j = 0; j < 4; j++) acc[i][j] = zz;
    for (int k0 = 0; k0 < 256; k0 += 32) {
        __syncthreads();
        const u16* a_src = A + (size_t)(m0 + srow) * 256 + k0 + scol;
        const u16* w_src = W + (size_t)(n0 + srow) * 256 + k0 + scol;
        *reinterpret_cast<bf16x8*>(&As[srow][scol]) =
            *reinterpret_cast<const bf16x8*>(a_src);
        *reinterpret_cast<bf16x8*>(&As[srow][scol + 8]) =
            *reinterpret_cast<const bf16x8*>(a_src + 8);
        *reinterpret_cast<bf16x8*>(&Bs[srow][scol]) =
            *reinterpret_cast<const bf16x8*>(w_src);
        *reinterpret_cast<bf16x8*>(&Bs[srow][scol + 8]) =
            *reinterpret_cast<const bf16x8*>(w_src + 8);
        __syncthreads();
        bf16x8 af[4], bfr[4];
#pragma unroll
        for (int mt = 0; mt < 4; mt++)
            af[mt] = *reinterpret_cast<const bf16x8*>(&As[wm + mt * 16 + l16][g * 8]);
#pragma unroll
        for (int nt = 0; nt < 4; nt++)
            bfr[nt] = *reinterpret_cast<const bf16x8*>(&Bs[wn + nt * 16 + l16][g * 8]);
#pragma unroll
        for (int mt = 0; mt < 4; mt++)
#pragma unroll
            for (int nt = 0; nt < 4; nt++)
                acc[mt][nt] = __builtin_amdgcn_mfma_f32_16x16x32_bf16(
                    af[mt], bfr[nt], acc[mt][nt], 0, 0, 0);
    }
    float bval[4];
#pragma unroll
    for (int nt = 0; nt < 4; nt++)
        bval[nt] = bias ? bias[n0 + wn + nt * 16 + l16] : 0.0f;
#pragma unroll
    for (int mt = 0; mt < 4; mt++)
#pragma unroll
        for (int r = 0; r < 4; r++) {
            int m = m0 + wm + mt * 16 + g * 4 + r;
#pragma unroll
            for (int nt = 0; nt < 4; nt++) {
                int n = n0 + wn + nt * 16 + l16;
                C[(size_t)m * Nout + n] = f2bf(acc[mt][nt][r] + bval[nt]);
            }
        }
}

// ---------------- depthwise 3x3 conv + bias + residual (bf16 io) ----------------
__global__ __launch_bounds__(256) void k_dwconv_add(const u16* __restrict__ yp,
                                                    const float* __restrict__ dw_w,
                                                    const float* __restrict__ dw_b,
                                                    u16* __restrict__ out) {
    int b = blockIdx.y;
    int n = blockIdx.x;
    int cc = threadIdx.x;
    int yy = n >> 5, xx = n & 31;
    const u16* ypb = yp + (size_t)b * N_ * C_;
    float acc = dw_b[cc];
#pragma unroll
    for (int dy = 0; dy < 3; dy++) {
        int y2 = yy + dy - 1;
        if (y2 < 0 || y2 >= 32) continue;
#pragma unroll
        for (int dx = 0; dx < 3; dx++) {
            int x2 = xx + dx - 1;
            if (x2 < 0 || x2 >= 32) continue;
            acc += bf2f(ypb[(size_t)(y2 * 32 + x2) * C_ + cc]) * dw_w[cc * 9 + dy * 3 + dx];
        }
    }
    out[(size_t)b * N_ * C_ + (size_t)n * C_ + cc] =
        f2bf(acc + bf2f(ypb[(size_t)n * C_ + cc]));
}

// ---------------- MFMA flash attention ----------------
// Q: [b][n][256] bf16 (head h at col h*64), K: kv buf [b][n][512] (K at h*64)
// Vt: [b][h][d][n] bf16.  4 waves x 16 q-rows, KV tiles of 64.
// STAGE 0: out = y[b][n][256] bf16;  STAGE 1: out = d_out f32 batch-mixing scatter
template <int STAGE>
__global__ __launch_bounds__(256) void k_attn_mfma(const u16* __restrict__ Q,
                                                   const u16* __restrict__ K,
                                                   const u16* __restrict__ Vt,
                                                   void* __restrict__ outp) {
    __shared__ u16 Ks[64][72];
    __shared__ u16 Vts[64][72];
    __shared__ u16 Ps[4][16][72];
    int qt = blockIdx.x, h = blockIdx.y, b = blockIdx.z;
    int q0 = qt * 64;
    int t = threadIdx.x;
    int wid = t >> 6, lane = t & 63;
    int l16 = lane & 15, g = lane >> 4;

    // Q fragments (held in regs for the whole kernel)
    const u16* Qrow = Q + ((size_t)(b * N_ + q0 + wid * 16 + l16)) * C_ + h * 64;
    bf16x8 qf[2];
    qf[0] = *reinterpret_cast<const bf16x8*>(Qrow + g * 8);
    qf[1] = *reinterpret_cast<const bf16x8*>(Qrow + 32 + g * 8);

    f32x4 zz = {0.f, 0.f, 0.f, 0.f};
    f32x4 accO[4];
#pragma unroll
    for (int dt = 0; dt < 4; dt++) accO[dt] = zz;
    float m_run[4] = {-1e30f, -1e30f, -1e30f, -1e30f};
    float l_run[4] = {0.f, 0.f, 0.f, 0.f};

    for (int kb = 0; kb < 16; kb++) {
        __syncthreads();
        // stage K tile [64][64] and Vt tile [64 d][64 kv]
#pragma unroll
        for (int e = 0; e < 2; e++) {
            int idx = t + e * 256;
            int row = idx >> 3, seg = idx & 7;
            *reinterpret_cast<bf16x8*>(&Ks[row][seg * 8]) =
                *reinterpret_cast<const bf16x8*>(
                    K + ((size_t)(b * N_ + kb * 64 + row)) * 512 + h * 64 + seg * 8);
            *reinterpret_cast<bf16x8*>(&Vts[row][seg * 8]) =
                *reinterpret_cast<const bf16x8*>(
                    Vt + ((size_t)((b * H_ + h) * 64 + row)) * N_ + kb * 64 + seg * 8);
        }
        __syncthreads();
        // S = Q . K^T  (4 kv-tiles of 16)
        f32x4 s[4];
#pragma unroll
        for (int nt = 0; nt < 4; nt++) s[nt] = zz;
#pragma unroll
        for (int nt = 0; nt < 4; nt++) {
            bf16x8 kf0 = *reinterpret_cast<const bf16x8*>(&Ks[nt * 16 + l16][g * 8]);
            bf16x8 kf1 = *reinterpret_cast<const bf16x8*>(&Ks[nt * 16 + l16][32 + g * 8]);
            s[nt] = __builtin_amdgcn_mfma_f32_16x16x32_bf16(qf[0], kf0, s[nt], 0, 0, 0);
            s[nt] = __builtin_amdgcn_mfma_f32_16x16x32_bf16(qf[1], kf1, s[nt], 0, 0, 0);
        }
        // online softmax (rows g*4+r, cols across l16 and nt)
        float fac[4];
#pragma unroll
        for (int r = 0; r < 4; r++) {
            float s0 = s[0][r] * 0.125f, s1 = s[1][r] * 0.125f;
            float s2 = s[2][r] * 0.125f, s3 = s[3][r] * 0.125f;
            float mt_ = fmaxf(fmaxf(s0, s1), fmaxf(s2, s3));
            mt_ = fmaxf(mt_, __shfl_xor(mt_, 1));
            mt_ = fmaxf(mt_, __shfl_xor(mt_, 2));
            mt_ = fmaxf(mt_, __shfl_xor(mt_, 4));
            mt_ = fmaxf(mt_, __shfl_xor(mt_, 8));
            float mnew = fmaxf(m_run[r], mt_);
            fac[r] = __expf(m_run[r] - mnew);
            m_run[r] = mnew;
            float p0 = __expf(s0 - mnew), p1 = __expf(s1 - mnew);
            float p2 = __expf(s2 - mnew), p3 = __expf(s3 - mnew);
            s[0][r] = p0; s[1][r] = p1; s[2][r] = p2; s[3][r] = p3;
            float ps = p0 + p1 + p2 + p3;
            ps += __shfl_xor(ps, 1);
            ps += __shfl_xor(ps, 2);
            ps += __shfl_xor(ps, 4);
            ps += __shfl_xor(ps, 8);
            l_run[r] = l_run[r] * fac[r] + ps;
        }
#pragma unroll
        for (int dt = 0; dt < 4; dt++)
#pragma unroll
            for (int r = 0; r < 4; r++) accO[dt][r] *= fac[r];
        // P (D-layout) -> per-wave LDS (A-layout source)
#pragma unroll
        for (int nt = 0; nt < 4; nt++)
#pragma unroll
            for (int r = 0; r < 4; r++)
                Ps[wid][g * 4 + r][nt * 16 + l16] = f2bf(s[nt][r]);
        // O += P . V   (2 kv-chunks of 32, 4 d-tiles)
#pragma unroll
        for (int kc = 0; kc < 2; kc++) {
            bf16x8 pf = *reinterpret_cast<const bf16x8*>(&Ps[wid][l16][kc * 32 + g * 8]);
#pragma unroll
            for (int dt = 0; dt < 4; dt++) {
                bf16x8 vf =
                    *reinterpret_cast<const bf16x8*>(&Vts[dt * 16 + l16][kc * 32 + g * 8]);
                accO[dt] = __builtin_amdgcn_mfma_f32_16x16x32_bf16(pf, vf, accO[dt], 0, 0, 0);
            }
        }
    }
    float inv[4];
#pragma unroll
    for (int r = 0; r < 4; r++) inv[r] = 1.0f / l_run[r];

    if (STAGE == 0) {
        u16* O = (u16*)outp;
#pragma unroll
        for (int dt = 0; dt < 4; dt++)
#pragma unroll
            for (int r = 0; r < 4; r++)
                O[((size_t)(b * N_ + q0 + wid * 16 + g * 4 + r)) * C_ + h * 64 +
                  dt * 16 + l16] = f2bf(accO[dt][r] * inv[r]);
    } else {
        __shared__ float Os[64][68];
#pragma unroll
        for (int dt = 0; dt < 4; dt++)
#pragma unroll
            for (int r = 0; r < 4; r++)
                Os[wid * 16 + g * 4 + r][dt * 16 + l16] = accO[dt][r] * inv[r];
        __syncthreads();
        // coalesced scatter: bo=(n&1)*8+h*2+(b>>3), co=((n>>1)&3)*64+d,
        // no=(b&7)*128+(n>>3); 8 consecutive no per 32B segment
        float* out = (float*)outp;
#pragma unroll
        for (int e = 0; e < 2; e++) {
            int seg = t + e * 256;
            int d = seg & 63, tb = seg >> 6;
            int tl = tb & 1, q2 = tb >> 1;
            int bo = tl * 8 + h * 2 + (b >> 3);
            int co = q2 * 64 + d;
            size_t base = (size_t)bo * (C_ * N_) + (size_t)co * N_ + (b & 7) * 128 + (q0 >> 3);
            float4 v0, v1;
            v0.x = Os[0 * 8 + q2 * 2 + tl][d];
            v0.y = Os[1 * 8 + q2 * 2 + tl][d];
            v0.z = Os[2 * 8 + q2 * 2 + tl][d];
            v0.w = Os[3 * 8 + q2 * 2 + tl][d];
            v1.x = Os[4 * 8 + q2 * 2 + tl][d];
            v1.y = Os[5 * 8 + q2 * 2 + tl][d];
            v1.z = Os[6 * 8 + q2 * 2 + tl][d];
            v1.w = Os[7 * 8 + q2 * 2 + tl][d];
            *reinterpret_cast<float4*>(&out[base]) = v0;
            *reinterpret_cast<float4*>(&out[base + 4]) = v1;
        }
    }
}

extern "C" void kernel_launch(void* const* d_in, const int* in_sizes, int n_in,
                              void* d_out, int out_size, void* d_ws, size_t ws_size,
                              hipStream_t stream) {
    const float* x      = (const float*)d_in[0];
    const float* q_w    = (const float*)d_in[1];
    const float* kv_w   = (const float*)d_in[2];
    const float* proj_w = (const float*)d_in[3];
    const float* proj_b = (const float*)d_in[4];
    const float* lq_w   = (const float*)d_in[5];
    const float* lq_b   = (const float*)d_in[6];
    const float* lkv_w  = (const float*)d_in[7];
    const float* lkv_b  = (const float*)d_in[8];
    // d_in[9] = rel_bias: constant along softmax axis -> no-op
    const float* dw_w   = (const float*)d_in[10];
    const float* dw_b   = (const float*)d_in[11];

    const size_t SZ = (size_t)B_ * N_ * C_;  // 4M elems
    u16* ws = (u16*)d_ws;
    u16* xf   = ws;            // [0, SZ)
    u16* qb   = ws + SZ;       // [SZ, 2SZ)
    u16* kvb  = ws + 2 * SZ;   // [2SZ, 4SZ)
    u16* Vt   = ws + 4 * SZ;   // [4SZ, 5SZ)
    u16* yb   = ws + 5 * SZ;   // [5SZ, 6SZ)
    u16* ypb  = qb;            // reuse
    u16* s2in = kvb;           // reuse (lower half)
    u16* q2b  = yb;            // reuse
    u16* kv2b = ws + 3 * SZ;   // [3SZ, 5SZ)
    u16* Vt2  = xf;            // reuse
    u16* wq   = ws + 6 * SZ;
    u16* wkv  = wq + 65536;
    u16* wproj= wkv + 131072;
    u16* wlq  = wproj + 65536;
    u16* wlkv = wlq + 65536;

    k_f2bf<<<64, 256, 0, stream>>>(q_w, wq, 16384);
    k_f2bf<<<128, 256, 0, stream>>>(kv_w, wkv, 32768);
    k_f2bf<<<64, 256, 0, stream>>>(proj_w, wproj, 16384);
    k_f2bf<<<64, 256, 0, stream>>>(lq_w, wlq, 16384);
    k_f2bf<<<128, 256, 0, stream>>>(lkv_w, wlkv, 32768);

    k_transpose_x<<<dim3(32, 8, B_), dim3(32, 8), 0, stream>>>(x, xf);
    k_gemm_bf16<<<dim3(2, 128), 256, 0, stream>>>(xf, wq, nullptr, qb, 256);
    k_gemm_bf16<<<dim3(4, 128), 256, 0, stream>>>(xf, wkv, nullptr, kvb, 512);
    k_transposeV<<<dim3(32, 8, B_), dim3(32, 8), 0, stream>>>(kvb, Vt);
    k_attn_mfma<0><<<dim3(16, H_, B_), 256, 0, stream>>>(qb, kvb, Vt, yb);
    k_gemm_bf16<<<dim3(2, 128), 256, 0, stream>>>(yb, wproj, proj_b, ypb, 256);
    k_dwconv_add<<<dim3(N_, B_), 256, 0, stream>>>(ypb, dw_w, dw_b, s2in);
    k_gemm_bf16<<<dim3(2, 128), 256, 0, stream>>>(xf, wlq, lq_b, q2b, 256);
    k_gemm_bf16<<<dim3(4, 128), 256, 0, stream>>>(s2in, wlkv, lkv_b, kv2b, 512);
    k_transposeV<<<dim3(32, 8, B_), dim3(32, 8), 0, stream>>>(kv2b, Vt2);
    k_attn_mfma<1><<<dim3(16, H_, B_), 256, 0, stream>>>(q2b, kv2b, Vt2, d_out);
}